// Round 12
// baseline (289.018 us; speedup 1.0000x reference)
//
#include <hip/hip_runtime.h>
#include <hip/hip_bf16.h>

// Problem constants (from reference)
#define DM   1024          // D_MODEL
#define NH   16            // heads
#define DH   64            // head dim per component
#define NSEQ 2048          // sequence length
#define NBATCH 2
#define ROWS (NBATCH*NSEQ) // 4096
#define QKVN (2*DM)        // 2048 = H * 2*Dh
#define STR3 (3*DM*2)      // 6144 = fused QKV row stride

typedef __attribute__((ext_vector_type(8))) short short8;
typedef __attribute__((ext_vector_type(4))) float f32x4;
typedef __attribute__((ext_vector_type(4))) unsigned short u16x4;

__device__ __forceinline__ unsigned short f2bf(float x) {
  union { float f; unsigned u; } v; v.f = x;
  unsigned r = v.u + 0x7FFFu + ((v.u >> 16) & 1u);
  return (unsigned short)(r >> 16);
}

__device__ __forceinline__ float exp2a(float x) {   // raw v_exp_f32 (2^x)
  float r; asm("v_exp_f32 %0, %1" : "=v"(r) : "v"(x)); return r;
}
__device__ __forceinline__ unsigned cvtpk(float lo, float hi) {  // 2xbf16 RNE pack
  unsigned d; asm("v_cvt_pk_bf16_f32 %0, %1, %2" : "=v"(d) : "v"(lo), "v"(hi)); return d;
}

__device__ __forceinline__ f32x4 mfma16(short8 a, short8 b, f32x4 c) {
  return __builtin_amdgcn_mfma_f32_16x16x32_bf16(a, b, c, 0, 0, 0);
}

#define GLL(src, dst) \
  __builtin_amdgcn_global_load_lds((const __attribute__((address_space(1))) void*)(src), \
                                   (__attribute__((address_space(3))) void*)(dst), 16, 0, 0)

#define WAITV(n) asm volatile("s_waitcnt vmcnt(" #n ")" ::: "memory")

// ---------------- fused prep: X cast + 4 weight transposes + lambda ----------------
// grid (64, 32, 5), block (32, 8).
//  z=0..2 : transpose+cast Wq/Wk/Wv ; z=3 : Wo ; z=4 : X cast (+ lam on blocks 0-3)
__global__ void prep_fused(const float* __restrict__ X,
                           const float* __restrict__ Wq, const float* __restrict__ Wk,
                           const float* __restrict__ Wv, const float* __restrict__ Wo,
                           const float* __restrict__ lq1, const float* __restrict__ lk1,
                           const float* __restrict__ lq2, const float* __restrict__ lk2,
                           unsigned short* __restrict__ Xb,
                           unsigned short* __restrict__ Wt,
                           unsigned short* __restrict__ Wot,
                           float* __restrict__ lamp) {
  const int z = blockIdx.z;
  const int tx = threadIdx.x, ty = threadIdx.y;

  if (z == 4) {               // X cast: 1M float4 total, 512 per block
    const int bid = blockIdx.y * 64 + blockIdx.x;
    const int t = ty * 32 + tx;
    #pragma unroll
    for (int j = 0; j < 2; ++j) {
      const int i = bid * 512 + j * 256 + t;     // float4 index
      f32x4 v = *(const f32x4*)(X + (size_t)i * 4);
      u16x4 o;
      #pragma unroll
      for (int k = 0; k < 4; ++k) o[k] = f2bf(v[k]);
      *(u16x4*)(Xb + (size_t)i * 4) = o;
    }
    if (bid < 4) {            // lambda: one wave per head (16 heads over 4 blocks)
      const int wv = t >> 6, lane = t & 63;
      const int h = bid * 4 + wv;
      float p1 = lq1[h*64 + lane] * lk1[h*64 + lane];
      float p2 = lq2[h*64 + lane] * lk2[h*64 + lane];
      #pragma unroll
      for (int mk = 32; mk >= 1; mk >>= 1) {
        p1 += __shfl_xor(p1, mk);
        p2 += __shfl_xor(p2, mk);
      }
      if (lane == 0) lamp[h] = expf(p1) - expf(p2) + 0.8f;
    }
    return;
  }

  const float* in;
  unsigned short* out;
  int R, C, bx, by;
  if (z < 3) {
    in = (z == 0) ? Wq : (z == 1) ? Wk : Wv;
    out = Wt + (size_t)z * 2048 * 1024;
    R = DM; C = QKVN;
    bx = blockIdx.x; by = blockIdx.y;
  } else {
    in = Wo; out = Wot;
    R = QKVN; C = DM;
    bx = blockIdx.y; by = blockIdx.x;
  }

  __shared__ float tile[32][33];
  #pragma unroll
  for (int i = 0; i < 4; ++i)
    tile[ty + i*8][tx] = in[(size_t)(by*32 + ty + i*8) * C + bx*32 + tx];
  __syncthreads();
  #pragma unroll
  for (int i = 0; i < 4; ++i)
    out[(size_t)(bx*32 + ty + i*8) * R + by*32 + tx] = f2bf(tile[tx][ty + i*8]);
}

// ---------------- transpose V slice of QKV (bf16, stride 6144) -> Vt[b][h][128][2048] ----------------
__global__ void transpose_v(const unsigned short* __restrict__ Vb, unsigned short* __restrict__ Vt) {
  __shared__ unsigned short tile[32][33];
  const int bx = blockIdx.x, by = blockIdx.y;
  const int tx = threadIdx.x, ty = threadIdx.y;
  #pragma unroll
  for (int i = 0; i < 4; ++i)
    tile[ty + i*8][tx] = Vb[(size_t)(by*32 + ty + i*8) * STR3 + bx*32 + tx];
  __syncthreads();
  #pragma unroll
  for (int i = 0; i < 4; ++i) {
    int colg = bx*32 + ty + i*8;   // 0..2047  -> (h, d)
    int rowg = by*32 + tx;         // 0..4095  -> (b, n)
    int hh = colg >> 7, dd = colg & 127;
    int bb = rowg >> 11, nn = rowg & 2047;
    Vt[(size_t)((bb*NH + hh)*128 + dd) * NSEQ + nn] = tile[tx][ty + i*8];
  }
}

// ---------------- 256x256 8-phase GEMM (T3+T4+T2+T5): C = A[M,K]*Bt[N,K]^T ----------------
template <typename OT>
__global__ __launch_bounds__(512) void gemm8p(const unsigned short* __restrict__ A,
                                              const unsigned short* __restrict__ Bt,
                                              OT* __restrict__ C, int M, int N, int K, int ldc) {
  __shared__ __align__(16) unsigned short As[2][2][256*32];   // 64 KB
  __shared__ __align__(16) unsigned short Bs[2][2][256*32];   // 64 KB
  (void)M; (void)N;
  const int tid = threadIdx.x;
  const int wv = tid >> 6, lane = tid & 63;
  const int l15 = lane & 15, lg = lane >> 4;
  const int wm = wv >> 2, wn = wv & 3;

  const unsigned gx = gridDim.x;
  unsigned bid = blockIdx.y * gx + blockIdx.x;
  const unsigned cpx = (gx * gridDim.y) >> 3;
  bid = (bid & 7u) * cpx + (bid >> 3);
  const int m0 = (int)(bid / gx) * 256, n0 = (int)(bid % gx) * 256;

  const int NT = K >> 6;

  int rowS[2], subS[2];
  #pragma unroll
  for (int j = 0; j < 2; ++j) {
    const int c = j*512 + tid;
    rowS[j] = c >> 2;
    const int s = c & 3;
    subS[j] = (s ^ (rowS[j] & 3) ^ ((rowS[j] >> 2) & 3)) & 3;
  }
  const unsigned short* Ab = A  + (size_t)m0 * K;
  const unsigned short* Bb = Bt + (size_t)n0 * K;

  auto stA = [&](int b, int ks, int tt) {
    #pragma unroll
    for (int j = 0; j < 2; ++j)
      GLL(Ab + (size_t)rowS[j]*K + tt*64 + ks*32 + subS[j]*8,
          &As[b][ks][(j*512 + (wv << 6)) * 8]);
  };
  auto stB = [&](int b, int ks, int tt) {
    #pragma unroll
    for (int j = 0; j < 2; ++j)
      GLL(Bb + (size_t)rowS[j]*K + tt*64 + ks*32 + subS[j]*8,
          &Bs[b][ks][(j*512 + (wv << 6)) * 8]);
  };

  const int phys = ((lg ^ (l15 & 3) ^ ((l15 >> 2) & 3)) & 3) * 8;

  auto rdA = [&](int b, int ks, int Mh, short8* af) {
    #pragma unroll
    for (int m = 0; m < 4; ++m) {
      const int row = wm*128 + Mh*64 + m*16 + l15;
      af[m] = *(const short8*)(&As[b][ks][row*32 + phys]);
    }
  };
  auto rdB = [&](int b, int ks, short8* bf) {
    #pragma unroll
    for (int n = 0; n < 4; ++n) {
      const int row = wn*64 + n*16 + l15;
      bf[n] = *(const short8*)(&Bs[b][ks][row*32 + phys]);
    }
  };

  f32x4 acc[8][4];
  #pragma unroll
  for (int i = 0; i < 8; ++i)
    #pragma unroll
    for (int j = 0; j < 4; ++j) acc[i][j] = f32x4{0.f, 0.f, 0.f, 0.f};

  stA(0, 0, 0); stB(0, 0, 0); stA(0, 1, 0); stB(0, 1, 0);
  stA(1, 0, 1); stB(1, 0, 1);
  WAITV(4);
  __builtin_amdgcn_s_barrier();

  short8 af[4], bf[4];

#define MFMA_CLUSTER(MH)                                               \
    asm volatile("s_waitcnt lgkmcnt(0)" ::: "memory");                 \
    __builtin_amdgcn_sched_barrier(0);                                 \
    __builtin_amdgcn_s_setprio(1);                                     \
    _Pragma("unroll")                                                  \
    for (int m = 0; m < 4; ++m)                                        \
      _Pragma("unroll")                                                \
      for (int n = 0; n < 4; ++n)                                      \
        acc[(MH)*4+m][n] = mfma16(af[m], bf[n], acc[(MH)*4+m][n]);     \
    __builtin_amdgcn_s_setprio(0);                                     \
    __builtin_amdgcn_s_barrier();

  for (int t = 0; t < NT; t += 2) {
    const bool s2 = (t + 2 < NT);
    const bool s3 = (t + 3 < NT);

    rdA(0, 0, 0, af); rdB(0, 0, bf);
    stA(1, 1, t + 1);
    __builtin_amdgcn_s_barrier();
    MFMA_CLUSTER(0)
    rdA(0, 0, 1, af);
    stB(1, 1, t + 1);
    __builtin_amdgcn_s_barrier();
    MFMA_CLUSTER(1)
    rdA(0, 1, 0, af); rdB(0, 1, bf);
    if (s2) stA(0, 0, t + 2);
    __builtin_amdgcn_s_barrier();
    MFMA_CLUSTER(0)
    rdA(0, 1, 1, af);
    if (s2) { stB(0, 0, t + 2); WAITV(4); } else { WAITV(0); }
    __builtin_amdgcn_s_barrier();
    MFMA_CLUSTER(1)
    rdA(1, 0, 0, af); rdB(1, 0, bf);
    if (s2) stA(0, 1, t + 2);
    __builtin_amdgcn_s_barrier();
    MFMA_CLUSTER(0)
    rdA(1, 0, 1, af);
    if (s2) stB(0, 1, t + 2);
    __builtin_amdgcn_s_barrier();
    MFMA_CLUSTER(1)
    rdA(1, 1, 0, af); rdB(1, 1, bf);
    if (s3) stA(1, 0, t + 3);
    __builtin_amdgcn_s_barrier();
    MFMA_CLUSTER(0)
    rdA(1, 1, 1, af);
    if (s3) stB(1, 0, t + 3);
    WAITV(4);
    __builtin_amdgcn_s_barrier();
    MFMA_CLUSTER(1)
  }
#undef MFMA_CLUSTER

  #pragma unroll
  for (int mi = 0; mi < 8; ++mi)
    #pragma unroll
    for (int n = 0; n < 4; ++n)
      #pragma unroll
      for (int r = 0; r < 4; ++r) {
        const int row = m0 + wm*128 + (mi >> 2)*64 + (mi & 3)*16 + lg*4 + r;
        const int col = n0 + wn*64 + n*16 + l15;
        if constexpr (sizeof(OT) == 2)
          C[(size_t)row * ldc + col] = f2bf(acc[mi][n][r]);
        else
          C[(size_t)row * ldc + col] = acc[mi][n][r];
      }
}

// ---------------- GEMM: C[M,N] = A[M,K] * Bt[N,K]^T  (m97 structure + T1) ----------------
template <typename OT>
__global__ __launch_bounds__(256) void gemm_bt(const unsigned short* __restrict__ A,
                                               const unsigned short* __restrict__ Bt,
                                               OT* __restrict__ C, int M, int N, int K) {
  __shared__ __align__(16) unsigned short As[128*32];
  __shared__ __align__(16) unsigned short Bs[128*32];
  const int tid = threadIdx.x;
  const int w = tid >> 6, lane = tid & 63;
  const int l15 = lane & 15, lg = lane >> 4;
  const int wr = w >> 1, wc = w & 1;

  const unsigned gx = gridDim.x;
  unsigned bid = blockIdx.y * gx + blockIdx.x;
  const unsigned cpx = (gx * gridDim.y) >> 3;
  bid = (bid & 7u) * cpx + (bid >> 3);
  const int m0 = (int)(bid / gx) * 128, n0 = (int)(bid % gx) * 128;

  f32x4 acc[4][4];
  #pragma unroll
  for (int i = 0; i < 4; ++i)
    #pragma unroll
    for (int j = 0; j < 4; ++j) acc[i][j] = f32x4{0.f, 0.f, 0.f, 0.f};

  for (int kt = 0; kt < K; kt += 32) {
    #pragma unroll
    for (int j = 0; j < 2; ++j) {
      int cbase = (j*4 + w) * 64;
      int c = cbase + lane;
      const unsigned short* ga = A + (size_t)(m0 + (c >> 2)) * K + kt + (c & 3) * 8;
      GLL(ga, As + cbase*8);
      const unsigned short* gb = Bt + (size_t)(n0 + (c >> 2)) * K + kt + (c & 3) * 8;
      GLL(gb, Bs + cbase*8);
    }
    __syncthreads();
    short8 af[4], bfr[4];
    #pragma unroll
    for (int m = 0; m < 4; ++m)
      af[m] = *(const short8*)(As + (wr*64 + m*16 + l15) * 32 + lg*8);
    #pragma unroll
    for (int n = 0; n < 4; ++n)
      bfr[n] = *(const short8*)(Bs + (wc*64 + n*16 + l15) * 32 + lg*8);
    #pragma unroll
    for (int m = 0; m < 4; ++m)
      #pragma unroll
      for (int n = 0; n < 4; ++n)
        acc[m][n] = mfma16(af[m], bfr[n], acc[m][n]);
    __syncthreads();
  }

  #pragma unroll
  for (int m = 0; m < 4; ++m)
    #pragma unroll
    for (int n = 0; n < 4; ++n)
      #pragma unroll
      for (int r = 0; r < 4; ++r) {
        int row = m0 + wr*64 + m*16 + lg*4 + r;
        int col = n0 + wc*64 + n*16 + l15;
        if constexpr (sizeof(OT) == 2)
          C[(size_t)row * N + col] = f2bf(acc[m][n][r]);
        else
          C[(size_t)row * N + col] = acc[m][n][r];
      }
}

// ---------------- differential flash attention + RMSNorm ----------------
// R5 champion structure + dual-component pipelining: the two attention
// components are independent until the epilogue, so the per-iteration chain
// is split: QK1 -> [max1-tree || QK2] -> defer1 -> exp1/pack1 -> fence ->
// PV1 (V frags captured in regs) -> softmax2 -> fence -> PV2 (reuses frags).
// Tree-shaped max/sum reductions (depth 4 vs 16-deep chains).
__global__ __launch_bounds__(256) void diff_attn(const unsigned short* __restrict__ QKV,
                                                 const unsigned short* __restrict__ Vt,
                                                 const float* __restrict__ lam_arr,
                                                 const float* __restrict__ rms_scale,
                                                 unsigned short* __restrict__ O) {
  __shared__ __align__(16) unsigned short Ks[2][64*128];   // 32 KB
  __shared__ __align__(16) unsigned short Vs[2][128*64];   // 32 KB
  __shared__ __align__(16) unsigned short Plds[4][2][16*64]; // 16 KB per-wave P staging

  const unsigned bid = blockIdx.x;
  const int xcd = (int)(bid & 7u), idx = (int)(bid >> 3);   // idx 0..63
  const int bh = xcd * 4 + (idx >> 4);
  const int jj = idx & 15;                                  // pair id 0..15

  const int b = bh >> 4, h = bh & 15;
  const int w = threadIdx.x >> 6, lane = threadIdx.x & 63;
  const int l15 = lane & 15, lg = lane >> 4;
  const float lam = lam_arr[h];

  const unsigned short* Qb  = QKV + (size_t)(b * NSEQ) * STR3 + h * 128;
  const unsigned short* Kb  = QKV + (size_t)(b * NSEQ) * STR3 + 2048 + h * 128;
  const unsigned short* Vtb = Vt + (size_t)bh * 128 * NSEQ;

  auto stage = [&](int bufi, int key0) {
    #pragma unroll
    for (int j = 0; j < 4; ++j) {
      const int t = j*4 + w;
      {
        const int row = t*4 + (lane >> 4);
        const int ck  = lane & 15;
        const int cks = (ck & 8) | ((ck ^ row) & 7);
        GLL(Kb + (size_t)(key0 + row) * STR3 + cks*8, &Ks[bufi][t*512]);
      }
      {
        const int row = t*8 + (lane >> 3);
        const int ck  = lane & 7;
        const int cks = (ck ^ row) & 7;
        GLL(Vtb + (size_t)row * NSEQ + key0 + cks*8, &Vs[bufi][t*512]);
      }
    }
  };

  char* pb0 = (char*)&Plds[w][0][0];
  char* pb1 = (char*)&Plds[w][1][0];
  const unsigned swz = (unsigned)((l15 & 7) << 4);
  const float qsc = 0.125f * 1.44269504088896340736f;
  const int kx0 = ((lg ^ l15) & 7) * 8;
  const int kx1 = (((4 + lg) ^ l15) & 7) * 8;

  for (int pass = 0; pass < 2; ++pass) {
    const int qt = pass ? jj : 31 - jj;       // long tile first
    const int q0 = qt * 64 + w * 16;

    short8 a1[2], a2[2];
    #pragma unroll
    for (int kc = 0; kc < 2; ++kc) {
      const unsigned short* qp = Qb + (size_t)(q0 + l15) * STR3 + kc*32 + lg*8;
      short8 r1 = *(const short8*)qp;
      short8 r2 = *(const short8*)(qp + 64);
      #pragma unroll
      for (int j = 0; j < 8; j += 2) {
        union { unsigned u; float f; } x0, x1, y0, y1;
        x0.u = ((unsigned)(unsigned short)r1[j]) << 16;
        x1.u = ((unsigned)(unsigned short)r1[j+1]) << 16;
        y0.u = ((unsigned)(unsigned short)r2[j]) << 16;
        y1.u = ((unsigned)(unsigned short)r2[j+1]) << 16;
        unsigned d1 = cvtpk(x0.f * qsc, x1.f * qsc);
        unsigned d2 = cvtpk(y0.f * qsc, y1.f * qsc);
        a1[kc][j]   = (short)(unsigned short)(d1 & 0xffffu);
        a1[kc][j+1] = (short)(unsigned short)(d1 >> 16);
        a2[kc][j]   = (short)(unsigned short)(d2 & 0xffffu);
        a2[kc][j+1] = (short)(unsigned short)(d2 >> 16);
      }
    }

    f32x4 o1[8], o2[8];
    #pragma unroll
    for (int i = 0; i < 8; ++i) { o1[i] = f32x4{0,0,0,0}; o2[i] = f32x4{0,0,0,0}; }
    float m1 = -3e38f, l1 = 0.f, m2 = -3e38f, l2 = 0.f;

    stage(0, 0);
    __syncthreads();
    int buf = 0;

    for (int kb = 0; kb <= qt; ++kb) {
      const int key0 = kb * 64;
      if (kb < qt) stage(buf ^ 1, key0 + 64);

      const unsigned short* Kbase = &Ks[buf][l15*128];

      // ---- QK^T component 1 ----
      f32x4 st1[4];
      #pragma unroll
      for (int nb = 0; nb < 4; ++nb) st1[nb] = f32x4{0,0,0,0};
      __builtin_amdgcn_s_setprio(1);
      #pragma unroll
      for (int nb = 0; nb < 4; ++nb) {
        const unsigned short* krow = Kbase + nb*2048;
        st1[nb] = mfma16(*(const short8*)(krow + kx0), a1[0], st1[nb]);
        st1[nb] = mfma16(*(const short8*)(krow + kx1), a1[1], st1[nb]);
      }
      __builtin_amdgcn_s_setprio(0);

      if (kb == qt) {
        #pragma unroll
        for (int nb = 0; nb < 4; ++nb)
          #pragma unroll
          for (int r = 0; r < 4; ++r)
            if (key0 + nb*16 + lg*4 + r > q0 + l15) st1[nb][r] = -3e38f;
      }

      // ---- max1 tree + QK^T component 2 (same BB -> scheduler interleaves) ----
      f32x4 st2[4];
      #pragma unroll
      for (int nb = 0; nb < 4; ++nb) st2[nb] = f32x4{0,0,0,0};
      float tm1;
      {
        f32x4 mA, mB;
        #pragma unroll
        for (int r = 0; r < 4; ++r) {
          mA[r] = fmaxf(st1[0][r], st1[1][r]);
          mB[r] = fmaxf(st1[2][r], st1[3][r]);
        }
        #pragma unroll
        for (int r = 0; r < 4; ++r) mA[r] = fmaxf(mA[r], mB[r]);
        tm1 = fmaxf(fmaxf(mA[0], mA[1]), fmaxf(mA[2], mA[3]));
      }
      #pragma unroll
      for (int nb = 0; nb < 4; ++nb) {
        const unsigned short* krow = Kbase + nb*2048;
        st2[nb] = mfma16(*(const short8*)(krow + kx0 + 64), a2[0], st2[nb]);
        st2[nb] = mfma16(*(const short8*)(krow + kx1 + 64), a2[1], st2[nb]);
      }
      tm1 = fmaxf(tm1, __shfl_xor(tm1, 16));
      tm1 = fmaxf(tm1, __shfl_xor(tm1, 32));

      // defer-max comp1
      if (__any(tm1 > m1 + 8.f)) {
        const float nm = fmaxf(m1, tm1);
        const float e = exp2a(m1 - nm);
        m1 = nm; l1 *= e;
        float er[4];
        #pragma unroll
        for (int r = 0; r < 4; ++r) er[r] = __shfl(e, lg*4 + r);
        #pragma unroll
        for (int i = 0; i < 8; ++i)
          #pragma unroll
          for (int r = 0; r < 4; ++r) o1[i][r] *= er[r];
      }

      // exp1 + tree sum + pack1
      #pragma unroll
      for (int nb = 0; nb < 4; ++nb)
        #pragma unroll
        for (int r = 0; r < 4; ++r) st1[nb][r] = exp2a(st1[nb][r] - m1);
      {
        f32x4 s4 = (st1[0] + st1[1]) + (st1[2] + st1[3]);
        float ts1 = (s4[0] + s4[1]) + (s4[2] + s4[3]);
        ts1 += __shfl_xor(ts1, 16); ts1 += __shfl_xor(ts1, 32); l1 += ts1;
      }
      #pragma unroll
      for (int nb = 0; nb < 4; ++nb) {
        const unsigned off = (unsigned)(l15*128 + nb*32 + lg*8) ^ swz;
        *(uint2*)(pb0 + off) = make_uint2(cvtpk(st1[nb][0], st1[nb][1]),
                                          cvtpk(st1[nb][2], st1[nb][3]));
      }

      // mask2 (diag only)
      if (kb == qt) {
        #pragma unroll
        for (int nb = 0; nb < 4; ++nb)
          #pragma unroll
          for (int r = 0; r < 4; ++r)
            if (key0 + nb*16 + lg*4 + r > q0 + l15) st2[nb][r] = -3e38f;
      }

      // fence for P1, read pa1
      asm volatile("s_waitcnt lgkmcnt(0)" ::: "memory");
      __builtin_amdgcn_sched_barrier(0);
      short8 pa1[2];
      pa1[0] = *(const short8*)(pb0 + ((unsigned)(l15*128 + 0*64 + lg*16) ^ swz));
      pa1[1] = *(const short8*)(pb0 + ((unsigned)(l15*128 + 1*64 + lg*16) ^ swz));
      __builtin_amdgcn_sched_barrier(0);

      // PV1 — capture V fragments for reuse by PV2
      short8 bva0[8], bva1[8];
      #pragma unroll
      for (int i = 0; i < 8; ++i) {
        const unsigned short* vrow = &Vs[buf][(i*16 + l15) * 64];
        bva0[i] = *(const short8*)(vrow + kx0);
        bva1[i] = *(const short8*)(vrow + kx1);
        o1[i] = mfma16(pa1[0], bva0[i], o1[i]);
        o1[i] = mfma16(pa1[1], bva1[i], o1[i]);
      }

      // softmax2 (independent of PV1 -> scheduler/other-wave overlap)
      float tm2;
      {
        f32x4 mA, mB;
        #pragma unroll
        for (int r = 0; r < 4; ++r) {
          mA[r] = fmaxf(st2[0][r], st2[1][r]);
          mB[r] = fmaxf(st2[2][r], st2[3][r]);
        }
        #pragma unroll
        for (int r = 0; r < 4; ++r) mA[r] = fmaxf(mA[r], mB[r]);
        tm2 = fmaxf(fmaxf(mA[0], mA[1]), fmaxf(mA[2], mA[3]));
      }
      tm2 = fmaxf(tm2, __shfl_xor(tm2, 16));
      tm2 = fmaxf(tm2, __shfl_xor(tm2, 32));

      if (__any(tm2 > m2 + 8.f)) {
        const float nm = fmaxf(m2, tm2);
        const float e = exp2a(m2 - nm);
        m2 = nm; l2 *= e;
        float er[4];
        #pragma unroll
        for (int r = 0; r < 4; ++r) er[r] = __shfl(e, lg*4 + r);
        #pragma unroll
        for (int i = 0; i < 8; ++i)
          #pragma unroll
          for (int r = 0; r < 4; ++r) o2[i][r] *= er[r];
      }

      #pragma unroll
      for (int nb = 0; nb < 4; ++nb)
        #pragma unroll
        for (int r = 0; r < 4; ++r) st2[nb][r] = exp2a(st2[nb][r] - m2);
      {
        f32x4 s4 = (st2[0] + st2[1]) + (st2[2] + st2[3]);
        float ts2 = (s4[0] + s4[1]) + (s4[2] + s4[3]);
        ts2 += __shfl_xor(ts2, 16); ts2 += __shfl_xor(ts2, 32); l2 += ts2;
      }
      #pragma unroll
      for (int nb = 0; nb < 4; ++nb) {
        const unsigned off = (unsigned)(l15*128 + nb*32 + lg*8) ^ swz;
        *(uint2*)(pb1 + off) = make_uint2(cvtpk(st2[nb][0], st2[nb][1]),
                                          cvtpk(st2[nb][2], st2[nb][3]));
      }

      // fence for P2, read pa2
      asm volatile("s_waitcnt lgkmcnt(0)" ::: "memory");
      __builtin_amdgcn_sched_barrier(0);
      short8 pa2[2];
      pa2[0] = *(const short8*)(pb1 + ((unsigned)(l15*128 + 0*64 + lg*16) ^ swz));
      pa2[1] = *(const short8*)(pb1 + ((unsigned)(l15*128 + 1*64 + lg*16) ^ swz));
      __builtin_amdgcn_sched_barrier(0);

      // PV2 — reuses captured V fragments (no V re-read)
      __builtin_amdgcn_s_setprio(1);
      #pragma unroll
      for (int i = 0; i < 8; ++i) {
        o2[i] = mfma16(pa2[0], bva0[i], o2[i]);
        o2[i] = mfma16(pa2[1], bva1[i], o2[i]);
      }
      __builtin_amdgcn_s_setprio(0);

      __syncthreads();
      buf ^= 1;
    }

    // epilogue: combine, RMSNorm over 128 dims, scale, store bf16
    float i1r[4], i2r[4];
    {
      const float inv1 = 1.f / l1, inv2 = 1.f / l2;
      #pragma unroll
      for (int r = 0; r < 4; ++r) {
        i1r[r] = __shfl(inv1, lg*4 + r);
        i2r[r] = __shfl(inv2, lg*4 + r);
      }
    }
    float ov[8][4];
    float ssq[4] = {0.f, 0.f, 0.f, 0.f};
    #pragma unroll
    for (int i = 0; i < 8; ++i)
      #pragma unroll
      for (int r = 0; r < 4; ++r) {
        float v = o1[i][r] * i1r[r] - lam * (o2[i][r] * i2r[r]);
        ov[i][r] = v;
        ssq[r] += v * v;
      }
    #pragma unroll
    for (int r = 0; r < 4; ++r)
      #pragma unroll
      for (int mk = 1; mk < 16; mk <<= 1) ssq[r] += __shfl_xor(ssq[r], mk);
    float rr[4];
    #pragma unroll
    for (int r = 0; r < 4; ++r) rr[r] = rsqrtf(ssq[r] * (1.f/128.f) + 1e-5f) * 0.2f;
    #pragma unroll
    for (int i = 0; i < 8; ++i) {
      const float sc = rms_scale[i*16 + l15];
      #pragma unroll
      for (int r = 0; r < 4; ++r) {
        const int q = q0 + lg*4 + r;
        O[(size_t)(b*NSEQ + q) * QKVN + h*128 + i*16 + l15] = f2bf(ov[i][r] * rr[r] * sc);
      }
    }
  }
}

extern "C" void kernel_launch(void* const* d_in, const int* in_sizes, int n_in,
                              void* d_out, int out_size, void* d_ws, size_t ws_size,
                              hipStream_t stream) {
  (void)in_sizes; (void)n_in; (void)out_size; (void)ws_size;
  const float* X   = (const float*)d_in[0];
  const float* Wq  = (const float*)d_in[1];
  const float* Wk  = (const float*)d_in[2];
  const float* Wv  = (const float*)d_in[3];
  const float* Wo  = (const float*)d_in[4];
  const float* lq1 = (const float*)d_in[5];
  const float* lk1 = (const float*)d_in[6];
  const float* lq2 = (const float*)d_in[7];
  const float* lk2 = (const float*)d_in[8];
  const float* rs  = (const float*)d_in[9];
  float* out = (float*)d_out;

  char* ws = (char*)d_ws;
  const size_t MB = 1ull << 20;
  unsigned short* Xb  = (unsigned short*)(ws);            // 0..8 MB
  unsigned short* Wt  = (unsigned short*)(ws + 8*MB);     // 8..20 MB
  unsigned short* Wot = (unsigned short*)(ws + 20*MB);    // 20..24 MB
  unsigned short* QKV = (unsigned short*)(ws + 24*MB);    // 24..72 MB: [4096][6144]
  unsigned short* Ob  = (unsigned short*)(ws + 72*MB);    // 72..88 MB
  float*          lamp = (float*)(ws + 88*MB);            // 64 B
  unsigned short* Vt  = (unsigned short*)(ws);            // 16 MB, overlays Xb+Wt (dead by then)

  prep_fused<<<dim3(64, 32, 5), dim3(32, 8), 0, stream>>>(
      X, Wq, Wk, Wv, Wo, lq1, lk1, lq2, lk2, Xb, Wt, Wot, lamp);

  // fused QKV projection, 8-phase 256^2: [4096][1024] x [6144][1024]^T -> [4096][6144]
  gemm8p<unsigned short><<<dim3(STR3/256, ROWS/256), 512, 0, stream>>>(
      Xb, Wt, QKV, ROWS, STR3, DM, STR3);

  transpose_v<<<dim3(QKVN/32, ROWS/32), dim3(32,8), 0, stream>>>(QKV + 4096, Vt);

  diff_attn<<<dim3(512), 256, 0, stream>>>(QKV, Vt, lamp, rs, Ob);

  gemm_bt<float><<<dim3(DM/128, ROWS/128), 256, 0, stream>>>(Ob, Wot, out, ROWS, DM, QKVN);
}

// Round 14
// 233.413 us; speedup vs baseline: 1.2382x; 1.2382x over previous
//
#include <hip/hip_runtime.h>
#include <hip/hip_bf16.h>

// Problem constants (from reference)
#define DM   1024          // D_MODEL
#define NH   16            // heads
#define DH   64            // head dim per component
#define NSEQ 2048          // sequence length
#define NBATCH 2
#define ROWS (NBATCH*NSEQ) // 4096
#define QKVN (2*DM)        // 2048 = H * 2*Dh
#define STR3 (3*DM*2)      // 6144 = fused QKV row stride

typedef __attribute__((ext_vector_type(8))) short short8;
typedef __attribute__((ext_vector_type(4))) float f32x4;
typedef __attribute__((ext_vector_type(4))) unsigned short u16x4;

__device__ __forceinline__ unsigned short f2bf(float x) {
  union { float f; unsigned u; } v; v.f = x;
  unsigned r = v.u + 0x7FFFu + ((v.u >> 16) & 1u);
  return (unsigned short)(r >> 16);
}

__device__ __forceinline__ float exp2a(float x) {   // raw v_exp_f32 (2^x)
  float r; asm("v_exp_f32 %0, %1" : "=v"(r) : "v"(x)); return r;
}
__device__ __forceinline__ unsigned cvtpk(float lo, float hi) {  // 2xbf16 RNE pack
  unsigned d; asm("v_cvt_pk_bf16_f32 %0, %1, %2" : "=v"(d) : "v"(lo), "v"(hi)); return d;
}

__device__ __forceinline__ f32x4 mfma16(short8 a, short8 b, f32x4 c) {
  return __builtin_amdgcn_mfma_f32_16x16x32_bf16(a, b, c, 0, 0, 0);
}

#define GLL(src, dst) \
  __builtin_amdgcn_global_load_lds((const __attribute__((address_space(1))) void*)(src), \
                                   (__attribute__((address_space(3))) void*)(dst), 16, 0, 0)

#define WAITV(n) asm volatile("s_waitcnt vmcnt(" #n ")" ::: "memory")

// ---------------- fused prep: X cast + 4 weight transposes + lambda ----------------
// grid (64, 32, 5), block (32, 8).
//  z=0..2 : transpose+cast Wq/Wk/Wv ; z=3 : Wo ; z=4 : X cast (+ lam on blocks 0-3)
__global__ void prep_fused(const float* __restrict__ X,
                           const float* __restrict__ Wq, const float* __restrict__ Wk,
                           const float* __restrict__ Wv, const float* __restrict__ Wo,
                           const float* __restrict__ lq1, const float* __restrict__ lk1,
                           const float* __restrict__ lq2, const float* __restrict__ lk2,
                           unsigned short* __restrict__ Xb,
                           unsigned short* __restrict__ Wt,
                           unsigned short* __restrict__ Wot,
                           float* __restrict__ lamp) {
  const int z = blockIdx.z;
  const int tx = threadIdx.x, ty = threadIdx.y;

  if (z == 4) {               // X cast: 1M float4 total, 512 per block
    const int bid = blockIdx.y * 64 + blockIdx.x;
    const int t = ty * 32 + tx;
    #pragma unroll
    for (int j = 0; j < 2; ++j) {
      const int i = bid * 512 + j * 256 + t;     // float4 index
      f32x4 v = *(const f32x4*)(X + (size_t)i * 4);
      u16x4 o;
      #pragma unroll
      for (int k = 0; k < 4; ++k) o[k] = f2bf(v[k]);
      *(u16x4*)(Xb + (size_t)i * 4) = o;
    }
    if (bid < 4) {            // lambda: one wave per head (16 heads over 4 blocks)
      const int wv = t >> 6, lane = t & 63;
      const int h = bid * 4 + wv;
      float p1 = lq1[h*64 + lane] * lk1[h*64 + lane];
      float p2 = lq2[h*64 + lane] * lk2[h*64 + lane];
      #pragma unroll
      for (int mk = 32; mk >= 1; mk >>= 1) {
        p1 += __shfl_xor(p1, mk);
        p2 += __shfl_xor(p2, mk);
      }
      if (lane == 0) lamp[h] = expf(p1) - expf(p2) + 0.8f;
    }
    return;
  }

  const float* in;
  unsigned short* out;
  int R, C, bx, by;
  if (z < 3) {
    in = (z == 0) ? Wq : (z == 1) ? Wk : Wv;
    out = Wt + (size_t)z * 2048 * 1024;
    R = DM; C = QKVN;
    bx = blockIdx.x; by = blockIdx.y;
  } else {
    in = Wo; out = Wot;
    R = QKVN; C = DM;
    bx = blockIdx.y; by = blockIdx.x;
  }

  __shared__ float tile[32][33];
  #pragma unroll
  for (int i = 0; i < 4; ++i)
    tile[ty + i*8][tx] = in[(size_t)(by*32 + ty + i*8) * C + bx*32 + tx];
  __syncthreads();
  #pragma unroll
  for (int i = 0; i < 4; ++i)
    out[(size_t)(bx*32 + ty + i*8) * R + by*32 + tx] = f2bf(tile[tx][ty + i*8]);
}

// ---------------- transpose V slice of QKV -> Vt[b][h][128][2048], vectorized ----------------
// 64x64 bf16 tile per block; short8 (16B) global loads AND stores (was 2B scalar).
// LDS transpose with pad-74 (load-scatter <=4-way conflict, ~free per m136).
// grid (QKVN/64=32, ROWS/64=64), block 256.
__global__ void transpose_v(const unsigned short* __restrict__ Vb, unsigned short* __restrict__ Vt) {
  __shared__ unsigned short T[64][74];
  const int t = threadIdx.x;
  const int bx = blockIdx.x, by = blockIdx.y;

  #pragma unroll
  for (int p = 0; p < 2; ++p) {
    const int r  = (t >> 3) + p * 32;        // source row within tile
    const int c0 = (t & 7) * 8;              // source col within tile
    short8 v = *(const short8*)(Vb + (size_t)(by*64 + r) * STR3 + bx*64 + c0);
    #pragma unroll
    for (int j = 0; j < 8; ++j) T[c0 + j][r] = (unsigned short)v[j];
  }
  __syncthreads();

  // block maps inside one head (64 | 128) and one batch (64 | 2048)
  const int hh  = bx >> 1;
  const int dd0 = (bx & 1) * 64;
  const int bb  = by >> 5;
  const int nn0 = (by & 31) * 64;

  const int dd = t >> 2;                     // 0..63
  const int g  = (t & 3) * 16;               // nn group base
  unsigned short* dst = Vt + ((size_t)((bb*NH + hh)*128 + dd0 + dd)) * NSEQ + nn0 + g;
  short8 w0, w1;
  #pragma unroll
  for (int j = 0; j < 8; ++j) { w0[j] = (short)T[dd][g + j]; w1[j] = (short)T[dd][g + 8 + j]; }
  *(short8*)dst = w0;
  *(short8*)(dst + 8) = w1;
}

// ---------------- 256x256 8-phase GEMM (T3+T4+T2+T5): C = A[M,K]*Bt[N,K]^T ----------------
template <typename OT>
__global__ __launch_bounds__(512) void gemm8p(const unsigned short* __restrict__ A,
                                              const unsigned short* __restrict__ Bt,
                                              OT* __restrict__ C, int M, int N, int K, int ldc) {
  __shared__ __align__(16) unsigned short As[2][2][256*32];   // 64 KB
  __shared__ __align__(16) unsigned short Bs[2][2][256*32];   // 64 KB
  (void)M; (void)N;
  const int tid = threadIdx.x;
  const int wv = tid >> 6, lane = tid & 63;
  const int l15 = lane & 15, lg = lane >> 4;
  const int wm = wv >> 2, wn = wv & 3;

  const unsigned gx = gridDim.x;
  unsigned bid = blockIdx.y * gx + blockIdx.x;
  const unsigned cpx = (gx * gridDim.y) >> 3;
  bid = (bid & 7u) * cpx + (bid >> 3);
  const int m0 = (int)(bid / gx) * 256, n0 = (int)(bid % gx) * 256;

  const int NT = K >> 6;

  int rowS[2], subS[2];
  #pragma unroll
  for (int j = 0; j < 2; ++j) {
    const int c = j*512 + tid;
    rowS[j] = c >> 2;
    const int s = c & 3;
    subS[j] = (s ^ (rowS[j] & 3) ^ ((rowS[j] >> 2) & 3)) & 3;
  }
  const unsigned short* Ab = A  + (size_t)m0 * K;
  const unsigned short* Bb = Bt + (size_t)n0 * K;

  auto stA = [&](int b, int ks, int tt) {
    #pragma unroll
    for (int j = 0; j < 2; ++j)
      GLL(Ab + (size_t)rowS[j]*K + tt*64 + ks*32 + subS[j]*8,
          &As[b][ks][(j*512 + (wv << 6)) * 8]);
  };
  auto stB = [&](int b, int ks, int tt) {
    #pragma unroll
    for (int j = 0; j < 2; ++j)
      GLL(Bb + (size_t)rowS[j]*K + tt*64 + ks*32 + subS[j]*8,
          &Bs[b][ks][(j*512 + (wv << 6)) * 8]);
  };

  const int phys = ((lg ^ (l15 & 3) ^ ((l15 >> 2) & 3)) & 3) * 8;

  auto rdA = [&](int b, int ks, int Mh, short8* af) {
    #pragma unroll
    for (int m = 0; m < 4; ++m) {
      const int row = wm*128 + Mh*64 + m*16 + l15;
      af[m] = *(const short8*)(&As[b][ks][row*32 + phys]);
    }
  };
  auto rdB = [&](int b, int ks, short8* bf) {
    #pragma unroll
    for (int n = 0; n < 4; ++n) {
      const int row = wn*64 + n*16 + l15;
      bf[n] = *(const short8*)(&Bs[b][ks][row*32 + phys]);
    }
  };

  f32x4 acc[8][4];
  #pragma unroll
  for (int i = 0; i < 8; ++i)
    #pragma unroll
    for (int j = 0; j < 4; ++j) acc[i][j] = f32x4{0.f, 0.f, 0.f, 0.f};

  stA(0, 0, 0); stB(0, 0, 0); stA(0, 1, 0); stB(0, 1, 0);
  stA(1, 0, 1); stB(1, 0, 1);
  WAITV(4);
  __builtin_amdgcn_s_barrier();

  short8 af[4], bf[4];

#define MFMA_CLUSTER(MH)                                               \
    asm volatile("s_waitcnt lgkmcnt(0)" ::: "memory");                 \
    __builtin_amdgcn_sched_barrier(0);                                 \
    __builtin_amdgcn_s_setprio(1);                                     \
    _Pragma("unroll")                                                  \
    for (int m = 0; m < 4; ++m)                                        \
      _Pragma("unroll")                                                \
      for (int n = 0; n < 4; ++n)                                      \
        acc[(MH)*4+m][n] = mfma16(af[m], bf[n], acc[(MH)*4+m][n]);     \
    __builtin_amdgcn_s_setprio(0);                                     \
    __builtin_amdgcn_s_barrier();

  for (int t = 0; t < NT; t += 2) {
    const bool s2 = (t + 2 < NT);
    const bool s3 = (t + 3 < NT);

    rdA(0, 0, 0, af); rdB(0, 0, bf);
    stA(1, 1, t + 1);
    __builtin_amdgcn_s_barrier();
    MFMA_CLUSTER(0)
    rdA(0, 0, 1, af);
    stB(1, 1, t + 1);
    __builtin_amdgcn_s_barrier();
    MFMA_CLUSTER(1)
    rdA(0, 1, 0, af); rdB(0, 1, bf);
    if (s2) stA(0, 0, t + 2);
    __builtin_amdgcn_s_barrier();
    MFMA_CLUSTER(0)
    rdA(0, 1, 1, af);
    if (s2) { stB(0, 0, t + 2); WAITV(4); } else { WAITV(0); }
    __builtin_amdgcn_s_barrier();
    MFMA_CLUSTER(1)
    rdA(1, 0, 0, af); rdB(1, 0, bf);
    if (s2) stA(0, 1, t + 2);
    __builtin_amdgcn_s_barrier();
    MFMA_CLUSTER(0)
    rdA(1, 0, 1, af);
    if (s2) stB(0, 1, t + 2);
    __builtin_amdgcn_s_barrier();
    MFMA_CLUSTER(1)
    rdA(1, 1, 0, af); rdB(1, 1, bf);
    if (s3) stA(1, 0, t + 3);
    __builtin_amdgcn_s_barrier();
    MFMA_CLUSTER(0)
    rdA(1, 1, 1, af);
    if (s3) stB(1, 0, t + 3);
    WAITV(4);
    __builtin_amdgcn_s_barrier();
    MFMA_CLUSTER(1)
  }
#undef MFMA_CLUSTER

  #pragma unroll
  for (int mi = 0; mi < 8; ++mi)
    #pragma unroll
    for (int n = 0; n < 4; ++n)
      #pragma unroll
      for (int r = 0; r < 4; ++r) {
        const int row = m0 + wm*128 + (mi >> 2)*64 + (mi & 3)*16 + lg*4 + r;
        const int col = n0 + wn*64 + n*16 + l15;
        if constexpr (sizeof(OT) == 2)
          C[(size_t)row * ldc + col] = f2bf(acc[mi][n][r]);
        else
          C[(size_t)row * ldc + col] = acc[mi][n][r];
      }
}

// ---------------- GEMM: C[M,N] = A[M,K] * Bt[N,K]^T  (m97 structure + T1) ----------------
template <typename OT>
__global__ __launch_bounds__(256) void gemm_bt(const unsigned short* __restrict__ A,
                                               const unsigned short* __restrict__ Bt,
                                               OT* __restrict__ C, int M, int N, int K) {
  __shared__ __align__(16) unsigned short As[128*32];
  __shared__ __align__(16) unsigned short Bs[128*32];
  const int tid = threadIdx.x;
  const int w = tid >> 6, lane = tid & 63;
  const int l15 = lane & 15, lg = lane >> 4;
  const int wr = w >> 1, wc = w & 1;

  const unsigned gx = gridDim.x;
  unsigned bid = blockIdx.y * gx + blockIdx.x;
  const unsigned cpx = (gx * gridDim.y) >> 3;
  bid = (bid & 7u) * cpx + (bid >> 3);
  const int m0 = (int)(bid / gx) * 128, n0 = (int)(bid % gx) * 128;

  f32x4 acc[4][4];
  #pragma unroll
  for (int i = 0; i < 4; ++i)
    #pragma unroll
    for (int j = 0; j < 4; ++j) acc[i][j] = f32x4{0.f, 0.f, 0.f, 0.f};

  for (int kt = 0; kt < K; kt += 32) {
    #pragma unroll
    for (int j = 0; j < 2; ++j) {
      int cbase = (j*4 + w) * 64;
      int c = cbase + lane;
      const unsigned short* ga = A + (size_t)(m0 + (c >> 2)) * K + kt + (c & 3) * 8;
      GLL(ga, As + cbase*8);
      const unsigned short* gb = Bt + (size_t)(n0 + (c >> 2)) * K + kt + (c & 3) * 8;
      GLL(gb, Bs + cbase*8);
    }
    __syncthreads();
    short8 af[4], bfr[4];
    #pragma unroll
    for (int m = 0; m < 4; ++m)
      af[m] = *(const short8*)(As + (wr*64 + m*16 + l15) * 32 + lg*8);
    #pragma unroll
    for (int n = 0; n < 4; ++n)
      bfr[n] = *(const short8*)(Bs + (wc*64 + n*16 + l15) * 32 + lg*8);
    #pragma unroll
    for (int m = 0; m < 4; ++m)
      #pragma unroll
      for (int n = 0; n < 4; ++n)
        acc[m][n] = mfma16(af[m], bfr[n], acc[m][n]);
    __syncthreads();
  }

  #pragma unroll
  for (int m = 0; m < 4; ++m)
    #pragma unroll
    for (int n = 0; n < 4; ++n)
      #pragma unroll
      for (int r = 0; r < 4; ++r) {
        int row = m0 + wr*64 + m*16 + lg*4 + r;
        int col = n0 + wc*64 + n*16 + l15;
        if constexpr (sizeof(OT) == 2)
          C[(size_t)row * N + col] = f2bf(acc[m][n][r]);
        else
          C[(size_t)row * N + col] = acc[m][n][r];
      }
}

// ---------------- differential flash attention + RMSNorm (R5/R10 champion, verbatim) ----------------
__global__ __launch_bounds__(256) void diff_attn(const unsigned short* __restrict__ QKV,
                                                 const unsigned short* __restrict__ Vt,
                                                 const float* __restrict__ lam_arr,
                                                 const float* __restrict__ rms_scale,
                                                 unsigned short* __restrict__ O) {
  __shared__ __align__(16) unsigned short Ks[2][64*128];   // 32 KB
  __shared__ __align__(16) unsigned short Vs[2][128*64];   // 32 KB
  __shared__ __align__(16) unsigned short Plds[4][2][16*64]; // 16 KB per-wave P staging

  const unsigned bid = blockIdx.x;
  const int xcd = (int)(bid & 7u), idx = (int)(bid >> 3);   // idx 0..63
  const int bh = xcd * 4 + (idx >> 4);
  const int jj = idx & 15;                                  // pair id 0..15

  const int b = bh >> 4, h = bh & 15;
  const int w = threadIdx.x >> 6, lane = threadIdx.x & 63;
  const int l15 = lane & 15, lg = lane >> 4;
  const float lam = lam_arr[h];

  const unsigned short* Qb  = QKV + (size_t)(b * NSEQ) * STR3 + h * 128;
  const unsigned short* Kb  = QKV + (size_t)(b * NSEQ) * STR3 + 2048 + h * 128;
  const unsigned short* Vtb = Vt + (size_t)bh * 128 * NSEQ;

  auto stage = [&](int bufi, int key0) {
    #pragma unroll
    for (int j = 0; j < 4; ++j) {
      const int t = j*4 + w;
      {
        const int row = t*4 + (lane >> 4);
        const int ck  = lane & 15;
        const int cks = (ck & 8) | ((ck ^ row) & 7);
        GLL(Kb + (size_t)(key0 + row) * STR3 + cks*8, &Ks[bufi][t*512]);
      }
      {
        const int row = t*8 + (lane >> 3);
        const int ck  = lane & 7;
        const int cks = (ck ^ row) & 7;
        GLL(Vtb + (size_t)row * NSEQ + key0 + cks*8, &Vs[bufi][t*512]);
      }
    }
  };

  char* pb0 = (char*)&Plds[w][0][0];
  char* pb1 = (char*)&Plds[w][1][0];
  const unsigned swz = (unsigned)((l15 & 7) << 4);
  const float qsc = 0.125f * 1.44269504088896340736f;
  const int kx0 = ((lg ^ l15) & 7) * 8;
  const int kx1 = (((4 + lg) ^ l15) & 7) * 8;

  for (int pass = 0; pass < 2; ++pass) {
    const int qt = pass ? jj : 31 - jj;       // long tile first
    const int q0 = qt * 64 + w * 16;

    short8 a1[2], a2[2];
    #pragma unroll
    for (int kc = 0; kc < 2; ++kc) {
      const unsigned short* qp = Qb + (size_t)(q0 + l15) * STR3 + kc*32 + lg*8;
      short8 r1 = *(const short8*)qp;
      short8 r2 = *(const short8*)(qp + 64);
      #pragma unroll
      for (int j = 0; j < 8; j += 2) {
        union { unsigned u; float f; } x0, x1, y0, y1;
        x0.u = ((unsigned)(unsigned short)r1[j]) << 16;
        x1.u = ((unsigned)(unsigned short)r1[j+1]) << 16;
        y0.u = ((unsigned)(unsigned short)r2[j]) << 16;
        y1.u = ((unsigned)(unsigned short)r2[j+1]) << 16;
        unsigned d1 = cvtpk(x0.f * qsc, x1.f * qsc);
        unsigned d2 = cvtpk(y0.f * qsc, y1.f * qsc);
        a1[kc][j]   = (short)(unsigned short)(d1 & 0xffffu);
        a1[kc][j+1] = (short)(unsigned short)(d1 >> 16);
        a2[kc][j]   = (short)(unsigned short)(d2 & 0xffffu);
        a2[kc][j+1] = (short)(unsigned short)(d2 >> 16);
      }
    }

    f32x4 o1[8], o2[8];
    #pragma unroll
    for (int i = 0; i < 8; ++i) { o1[i] = f32x4{0,0,0,0}; o2[i] = f32x4{0,0,0,0}; }
    float m1 = -3e38f, l1 = 0.f, m2 = -3e38f, l2 = 0.f;

    stage(0, 0);
    __syncthreads();
    int buf = 0;

    for (int kb = 0; kb <= qt; ++kb) {
      const int key0 = kb * 64;
      if (kb < qt) stage(buf ^ 1, key0 + 64);

      f32x4 st1[4], st2[4];
      #pragma unroll
      for (int nb = 0; nb < 4; ++nb) { st1[nb] = f32x4{0,0,0,0}; st2[nb] = f32x4{0,0,0,0}; }
      __builtin_amdgcn_s_setprio(1);
      #pragma unroll
      for (int nb = 0; nb < 4; ++nb) {
        const unsigned short* krow = &Ks[buf][nb*2048 + l15*128];
        short8 k10 = *(const short8*)(krow + kx0);
        short8 k11 = *(const short8*)(krow + kx1);
        short8 k20 = *(const short8*)(krow + kx0 + 64);
        short8 k21 = *(const short8*)(krow + kx1 + 64);
        st1[nb] = mfma16(k10, a1[0], st1[nb]);
        st1[nb] = mfma16(k11, a1[1], st1[nb]);
        st2[nb] = mfma16(k20, a2[0], st2[nb]);
        st2[nb] = mfma16(k21, a2[1], st2[nb]);
      }
      __builtin_amdgcn_s_setprio(0);

      if (kb == qt) {
        #pragma unroll
        for (int nb = 0; nb < 4; ++nb)
          #pragma unroll
          for (int r = 0; r < 4; ++r)
            if (key0 + nb*16 + lg*4 + r > q0 + l15) { st1[nb][r] = -3e38f; st2[nb][r] = -3e38f; }
      }

      float tm1 = -3e38f, tm2 = -3e38f;
      #pragma unroll
      for (int nb = 0; nb < 4; ++nb)
        #pragma unroll
        for (int r = 0; r < 4; ++r) {
          tm1 = fmaxf(tm1, st1[nb][r]); tm2 = fmaxf(tm2, st2[nb][r]);
        }
      tm1 = fmaxf(tm1, __shfl_xor(tm1, 16));
      tm1 = fmaxf(tm1, __shfl_xor(tm1, 32));
      tm2 = fmaxf(tm2, __shfl_xor(tm2, 16));
      tm2 = fmaxf(tm2, __shfl_xor(tm2, 32));

      if (__any(tm1 > m1 + 8.f)) {
        const float nm = fmaxf(m1, tm1);
        const float e = exp2a(m1 - nm);
        m1 = nm; l1 *= e;
        float er[4];
        #pragma unroll
        for (int r = 0; r < 4; ++r) er[r] = __shfl(e, lg*4 + r);
        #pragma unroll
        for (int i = 0; i < 8; ++i)
          #pragma unroll
          for (int r = 0; r < 4; ++r) o1[i][r] *= er[r];
      }
      if (__any(tm2 > m2 + 8.f)) {
        const float nm = fmaxf(m2, tm2);
        const float e = exp2a(m2 - nm);
        m2 = nm; l2 *= e;
        float er[4];
        #pragma unroll
        for (int r = 0; r < 4; ++r) er[r] = __shfl(e, lg*4 + r);
        #pragma unroll
        for (int i = 0; i < 8; ++i)
          #pragma unroll
          for (int r = 0; r < 4; ++r) o2[i][r] *= er[r];
      }

      float ts1 = 0.f, ts2 = 0.f;
      #pragma unroll
      for (int nb = 0; nb < 4; ++nb)
        #pragma unroll
        for (int r = 0; r < 4; ++r) {
          st1[nb][r] = exp2a(st1[nb][r] - m1); ts1 += st1[nb][r];
          st2[nb][r] = exp2a(st2[nb][r] - m2); ts2 += st2[nb][r];
        }
      ts1 += __shfl_xor(ts1, 16); ts1 += __shfl_xor(ts1, 32); l1 += ts1;
      ts2 += __shfl_xor(ts2, 16); ts2 += __shfl_xor(ts2, 32); l2 += ts2;

      #pragma unroll
      for (int nb = 0; nb < 4; ++nb) {
        const unsigned off = (unsigned)(l15*128 + nb*32 + lg*8) ^ swz;
        *(uint2*)(pb0 + off) = make_uint2(cvtpk(st1[nb][0], st1[nb][1]),
                                          cvtpk(st1[nb][2], st1[nb][3]));
        *(uint2*)(pb1 + off) = make_uint2(cvtpk(st2[nb][0], st2[nb][1]),
                                          cvtpk(st2[nb][2], st2[nb][3]));
      }
      asm volatile("s_waitcnt lgkmcnt(0)" ::: "memory");
      __builtin_amdgcn_sched_barrier(0);
      short8 pa1[2], pa2[2];
      #pragma unroll
      for (int kc = 0; kc < 2; ++kc) {
        const unsigned off = (unsigned)(l15*128 + kc*64 + lg*16) ^ swz;
        pa1[kc] = *(const short8*)(pb0 + off);
        pa2[kc] = *(const short8*)(pb1 + off);
      }
      __builtin_amdgcn_sched_barrier(0);

      __builtin_amdgcn_s_setprio(1);
      #pragma unroll
      for (int i = 0; i < 8; ++i) {
        const unsigned short* vrow = &Vs[buf][(i*16 + l15) * 64];
        const short8 b0 = *(const short8*)(vrow + kx0);
        const short8 b1 = *(const short8*)(vrow + kx1);
        o1[i] = mfma16(pa1[0], b0, o1[i]);
        o2[i] = mfma16(pa2[0], b0, o2[i]);
        o1[i] = mfma16(pa1[1], b1, o1[i]);
        o2[i] = mfma16(pa2[1], b1, o2[i]);
      }
      __builtin_amdgcn_s_setprio(0);

      __syncthreads();
      buf ^= 1;
    }

    float i1r[4], i2r[4];
    {
      const float inv1 = 1.f / l1, inv2 = 1.f / l2;
      #pragma unroll
      for (int r = 0; r < 4; ++r) {
        i1r[r] = __shfl(inv1, lg*4 + r);
        i2r[r] = __shfl(inv2, lg*4 + r);
      }
    }
    float ov[8][4];
    float ssq[4] = {0.f, 0.f, 0.f, 0.f};
    #pragma unroll
    for (int i = 0; i < 8; ++i)
      #pragma unroll
      for (int r = 0; r < 4; ++r) {
        float v = o1[i][r] * i1r[r] - lam * (o2[i][r] * i2r[r]);
        ov[i][r] = v;
        ssq[r] += v * v;
      }
    #pragma unroll
    for (int r = 0; r < 4; ++r)
      #pragma unroll
      for (int mk = 1; mk < 16; mk <<= 1) ssq[r] += __shfl_xor(ssq[r], mk);
    float rr[4];
    #pragma unroll
    for (int r = 0; r < 4; ++r) rr[r] = rsqrtf(ssq[r] * (1.f/128.f) + 1e-5f) * 0.2f;
    #pragma unroll
    for (int i = 0; i < 8; ++i) {
      const float sc = rms_scale[i*16 + l15];
      #pragma unroll
      for (int r = 0; r < 4; ++r) {
        const int q = q0 + lg*4 + r;
        O[(size_t)(b*NSEQ + q) * QKVN + h*128 + i*16 + l15] = f2bf(ov[i][r] * rr[r] * sc);
      }
    }
  }
}

extern "C" void kernel_launch(void* const* d_in, const int* in_sizes, int n_in,
                              void* d_out, int out_size, void* d_ws, size_t ws_size,
                              hipStream_t stream) {
  (void)in_sizes; (void)n_in; (void)out_size; (void)ws_size;
  const float* X   = (const float*)d_in[0];
  const float* Wq  = (const float*)d_in[1];
  const float* Wk  = (const float*)d_in[2];
  const float* Wv  = (const float*)d_in[3];
  const float* Wo  = (const float*)d_in[4];
  const float* lq1 = (const float*)d_in[5];
  const float* lk1 = (const float*)d_in[6];
  const float* lq2 = (const float*)d_in[7];
  const float* lk2 = (const float*)d_in[8];
  const float* rs  = (const float*)d_in[9];
  float* out = (float*)d_out;

  char* ws = (char*)d_ws;
  const size_t MB = 1ull << 20;
  unsigned short* Xb  = (unsigned short*)(ws);            // 0..8 MB
  unsigned short* Wt  = (unsigned short*)(ws + 8*MB);     // 8..20 MB
  unsigned short* Wot = (unsigned short*)(ws + 20*MB);    // 20..24 MB
  unsigned short* QKV = (unsigned short*)(ws + 24*MB);    // 24..72 MB: [4096][6144]
  unsigned short* Ob  = (unsigned short*)(ws + 72*MB);    // 72..88 MB
  float*          lamp = (float*)(ws + 88*MB);            // 64 B
  unsigned short* Vt  = (unsigned short*)(ws);            // 16 MB, overlays Xb+Wt (dead by then)

  prep_fused<<<dim3(64, 32, 5), dim3(32, 8), 0, stream>>>(
      X, Wq, Wk, Wv, Wo, lq1, lk1, lq2, lk2, Xb, Wt, Wot, lamp);

  // fused QKV projection, 8-phase 256^2: [4096][1024] x [6144][1024]^T -> [4096][6144]
  gemm8p<unsigned short><<<dim3(STR3/256, ROWS/256), 512, 0, stream>>>(
      Xb, Wt, QKV, ROWS, STR3, DM, STR3);

  transpose_v<<<dim3(QKVN/64, ROWS/64), 256, 0, stream>>>(QKV + 4096, Vt);

  diff_attn<<<dim3(512), 256, 0, stream>>>(QKV, Vt, lamp, rs, Ob);

  gemm_bt<float><<<dim3(DM/128, ROWS/128), 256, 0, stream>>>(Ob, Wot, out, ROWS, DM, QKVN);
}